// Round 12
// baseline (111.113 us; speedup 1.0000x reference)
//
#include <hip/hip_runtime.h>
#include <math.h>

typedef float f32x4 __attribute__((ext_vector_type(4)));
typedef __bf16 bf16x8 __attribute__((ext_vector_type(8)));
typedef unsigned short u16x8 __attribute__((ext_vector_type(8)));

__device__ __forceinline__ unsigned short f2bf(float f) {
    union { float f; unsigned int u; } v; v.f = f;
    unsigned int u = v.u;
    return (unsigned short)((u + 0x7fffu + ((u >> 16) & 1u)) >> 16);  // RNE
}
__device__ __forceinline__ float bf_lo(unsigned int d) {
    union { unsigned int u; float f; } v; v.u = d << 16; return v.f;
}
__device__ __forceinline__ float bf_hi(unsigned int d) {
    union { unsigned int u; float f; } v; v.u = d & 0xffff0000u; return v.f;
}
__device__ __forceinline__ unsigned int u4get(const uint4& v, int k) {
    return k == 0 ? v.x : k == 1 ? v.y : k == 2 ? v.z : v.w;  // k compile-time
}
__device__ __forceinline__ float sigmoidf_(float v) {
    return 1.f / (1.f + __expf(-v));
}

// ---------------------------------------------------------------------------
// Kernel 1: fused convert + MFMA bf16 GEMM.  C[m][n] = sum_w A[m][w]*B[n][w].
//  left  (t<32):  A = x^T tile (transpose+cvt in LDS), B = W[e][0:256]
//                 -> Lp[b][k][e] = C + b_lin[e]   (fp32)
//  right (t>=32): A = W[e][256:512], B = x^T tile
//                 -> R2[b][(e>>3)*2048 + j*8 + (e&7)] = bf16(C)
// ---------------------------------------------------------------------------
__global__ __launch_bounds__(256) void mfma_gemm_kernel(
    const float* __restrict__ x,      // (8,256,256) x[b][w][k]
    const float* __restrict__ W,      // (512,512)
    const float* __restrict__ b_lin,  // (512)
    float* __restrict__ Lp,           // (8,256,512)
    unsigned short* __restrict__ R2)  // (8, 512e x 256j packed)
{
    const int b = blockIdx.y;
    const int t = blockIdx.x;
    const bool left = (t < 32);
    int m0, n0;
    if (left) { m0 = (t >> 3) * 64; n0 = (t & 7) * 64; }
    else      { const int tt = t - 32; m0 = (tt >> 2) * 64; n0 = (tt & 3) * 64; }

    __shared__ unsigned short As[64][72];
    __shared__ unsigned short Bs[64][72];

    unsigned short (*Ts)[72] = left ? As : Bs;   // x^T tile
    unsigned short (*Ds)[72] = left ? Bs : As;   // W tile
    const int cbase = left ? m0 : n0;            // x column base (k or j)
    const int rbase = left ? n0 : m0;            // W row base (e)
    const int coff  = left ? 0 : 256;            // W column offset

    const int tid  = threadIdx.x;
    const int wv   = tid >> 6;
    const int lane = tid & 63;
    const int wy = wv >> 1, wx = wv & 1;
    const int lr = lane & 15;
    const int lk = lane >> 4;

    const float* xb = x + b * 65536;

    f32x4 acc[2][2];
    #pragma unroll
    for (int i = 0; i < 2; i++)
        #pragma unroll
        for (int jj = 0; jj < 2; jj++) acc[i][jj] = (f32x4){0.f, 0.f, 0.f, 0.f};

    const int wl = tid >> 4;         // 0..15
    const int kg = tid & 15;         // 0..15
    const int dr = tid >> 2;         // 0..63
    const int dc = (tid & 3) * 16;

    for (int k0 = 0; k0 < 256; k0 += 64) {
        #pragma unroll
        for (int p = 0; p < 4; p++) {
            const int w = wl + 16 * p;
            const float4 v = *(const float4*)(xb + (k0 + w) * 256 + cbase + kg * 4);
            Ts[kg * 4 + 0][w] = f2bf(v.x);
            Ts[kg * 4 + 1][w] = f2bf(v.y);
            Ts[kg * 4 + 2][w] = f2bf(v.z);
            Ts[kg * 4 + 3][w] = f2bf(v.w);
        }
        {
            const float* src = W + (rbase + dr) * 512 + coff + k0 + dc;
            const float4 v0 = *(const float4*)(src);
            const float4 v1 = *(const float4*)(src + 4);
            const float4 v2 = *(const float4*)(src + 8);
            const float4 v3 = *(const float4*)(src + 12);
            u16x8 o0, o1;
            o0[0] = f2bf(v0.x); o0[1] = f2bf(v0.y); o0[2] = f2bf(v0.z); o0[3] = f2bf(v0.w);
            o0[4] = f2bf(v1.x); o0[5] = f2bf(v1.y); o0[6] = f2bf(v1.z); o0[7] = f2bf(v1.w);
            o1[0] = f2bf(v2.x); o1[1] = f2bf(v2.y); o1[2] = f2bf(v2.z); o1[3] = f2bf(v2.w);
            o1[4] = f2bf(v3.x); o1[5] = f2bf(v3.y); o1[6] = f2bf(v3.z); o1[7] = f2bf(v3.w);
            *(u16x8*)&Ds[dr][dc]     = o0;
            *(u16x8*)&Ds[dr][dc + 8] = o1;
        }
        __syncthreads();
        #pragma unroll
        for (int kk = 0; kk < 64; kk += 32) {
            const bf16x8 a0 = *(const bf16x8*)&As[wy * 32 + lr][kk + lk * 8];
            const bf16x8 a1 = *(const bf16x8*)&As[wy * 32 + 16 + lr][kk + lk * 8];
            const bf16x8 b0 = *(const bf16x8*)&Bs[wx * 32 + lr][kk + lk * 8];
            const bf16x8 b1 = *(const bf16x8*)&Bs[wx * 32 + 16 + lr][kk + lk * 8];
            acc[0][0] = __builtin_amdgcn_mfma_f32_16x16x32_bf16(a0, b0, acc[0][0], 0, 0, 0);
            acc[0][1] = __builtin_amdgcn_mfma_f32_16x16x32_bf16(a0, b1, acc[0][1], 0, 0, 0);
            acc[1][0] = __builtin_amdgcn_mfma_f32_16x16x32_bf16(a1, b0, acc[1][0], 0, 0, 0);
            acc[1][1] = __builtin_amdgcn_mfma_f32_16x16x32_bf16(a1, b1, acc[1][1], 0, 0, 0);
        }
        __syncthreads();
    }

    // C/D layout: col = lane&15, row = (lane>>4)*4 + reg
    if (left) {
        #pragma unroll
        for (int mi = 0; mi < 2; mi++) {
            #pragma unroll
            for (int ni = 0; ni < 2; ni++) {
                const int row = m0 + wy * 32 + mi * 16 + lk * 4;   // k
                const int col = n0 + wx * 32 + ni * 16 + lr;       // e
                const float bl = b_lin[col];
                #pragma unroll
                for (int r = 0; r < 4; r++)
                    Lp[b * 131072 + (row + r) * 512 + col] = acc[mi][ni][r] + bl;
            }
        }
    } else {
        unsigned short* R2b = R2 + b * 131072;
        #pragma unroll
        for (int mi = 0; mi < 2; mi++) {
            #pragma unroll
            for (int ni = 0; ni < 2; ni++) {
                const int row = m0 + wy * 32 + mi * 16 + lk * 4;   // e base (4)
                const int col = n0 + wx * 32 + ni * 16 + lr;       // j
                ushort4 o;
                o.x = f2bf(acc[mi][ni][0]);
                o.y = f2bf(acc[mi][ni][1]);
                o.z = f2bf(acc[mi][ni][2]);
                o.w = f2bf(acc[mi][ni][3]);
                *(ushort4*)(R2b + (row >> 3) * 2048 + col * 8 + (row & 7)) = o;
            }
        }
    }
}

// ---------------------------------------------------------------------------
// Kernel 2: score partials only.
// grid 1024 = (i4-tile 64 x e-half 2) x (b = blk&7, XCD-local); 512 thr.
// Wave = 32-e octant within the half, lane = j-quad. One Lt b128 broadcast
// per e feeds 4i x 4j fma-abs. LDS 37KB -> 4 blocks/CU; grid 1024 = 4/CU
// exactly -> 32 waves/CU (100%). Output: P[blk][4][256] fp32 block partials
// (with 1.5*rsum folded: score = u15 + 0.4*(P0+P1) + bias).
// ---------------------------------------------------------------------------
__global__ __launch_bounds__(512, 4) void attn_score_kernel(
    const float* __restrict__ Lp,             // (8,256,512) fp32, b_lin folded
    const unsigned int* __restrict__ R2u,     // packed bf16 pairs
    const float* __restrict__ a,              // (512)
    float* __restrict__ P)                    // (1024,4,256) fp32 partials
{
    const int b    = blockIdx.x & 7;
    const int ih   = blockIdx.x >> 3;         // 0..127 = i4*2 + half
    const int i0   = (ih >> 1) * 4;
    const int half = ih & 1;
    const int tid  = threadIdx.x;
    const int wv   = tid >> 6;                // 0..7 = 32-e octant
    const int lane = tid & 63;                // j-quad index

    __shared__ float Lt[256][4];              // 4 KB  [e'][i] transposed L
    __shared__ float aS[256];                 // 1 KB
    __shared__ float acc2P[8][4][256];        // 32 KB [oct][i][j]

    // ---- stage Lt (this half's 256 e) + aS
    {
        const int i  = tid >> 7;              // 0..3
        const int e0 = (tid & 127) * 2;       // 0..254
        const float2 v = *(const float2*)(Lp + b * 131072 + (i0 + i) * 512
                                          + half * 256 + e0);
        Lt[e0 + 0][i] = v.x;
        Lt[e0 + 1][i] = v.y;
    }
    if (tid < 256) aS[tid] = a[half * 256 + tid];
    __syncthreads();

    // ---- score: wave covers e' in [wv*32, wv*32+32), lane covers 4 j
    const float* aq = aS + wv * 32;
    const float (*Ltq)[4] = (const float (*)[4])(Lt + wv * 32);
    const uint4* Rq = (const uint4*)(R2u + b * 65536)
                    + (half * 32 + wv * 4) * 256 + lane * 4;

    float acc[4][4];                          // [i][jj]
    #pragma unroll
    for (int i = 0; i < 4; i++)
        #pragma unroll
        for (int jj = 0; jj < 4; jj++) acc[i][jj] = 0.f;
    float rsum[4] = {0.f, 0.f, 0.f, 0.f};

    uint4 c0 = Rq[0], c1 = Rq[1], c2 = Rq[2], c3 = Rq[3];
    #pragma unroll 1
    for (int tk = 0; tk < 4; tk++) {
        uint4 n0_, n1_, n2_, n3_;
        if (tk < 3) {
            const uint4* Rn = Rq + (tk + 1) * 256;
            n0_ = Rn[0]; n1_ = Rn[1]; n2_ = Rn[2]; n3_ = Rn[3];
        }
        const float4 av0 = *(const float4*)&aq[tk * 8];
        const float4 av1 = *(const float4*)&aq[tk * 8 + 4];
        #pragma unroll
        for (int s = 0; s < 8; s++) {
            const float4 lv = *(const float4*)Ltq[tk * 8 + s];  // b128 bcast
            const float ae = (s < 4) ? ((const float*)&av0)[s]
                                     : ((const float*)&av1)[s - 4];
            const int dwi = s >> 1;
            const bool hi = s & 1;
            const float r0 = hi ? bf_hi(u4get(c0, dwi)) : bf_lo(u4get(c0, dwi));
            const float r1 = hi ? bf_hi(u4get(c1, dwi)) : bf_lo(u4get(c1, dwi));
            const float r2 = hi ? bf_hi(u4get(c2, dwi)) : bf_lo(u4get(c2, dwi));
            const float r3 = hi ? bf_hi(u4get(c3, dwi)) : bf_lo(u4get(c3, dwi));
            rsum[0] = fmaf(ae, r0, rsum[0]);
            rsum[1] = fmaf(ae, r1, rsum[1]);
            rsum[2] = fmaf(ae, r2, rsum[2]);
            rsum[3] = fmaf(ae, r3, rsum[3]);
            acc[0][0] = fmaf(ae, fabsf(lv.x + r0), acc[0][0]);
            acc[1][0] = fmaf(ae, fabsf(lv.y + r0), acc[1][0]);
            acc[2][0] = fmaf(ae, fabsf(lv.z + r0), acc[2][0]);
            acc[3][0] = fmaf(ae, fabsf(lv.w + r0), acc[3][0]);
            acc[0][1] = fmaf(ae, fabsf(lv.x + r1), acc[0][1]);
            acc[1][1] = fmaf(ae, fabsf(lv.y + r1), acc[1][1]);
            acc[2][1] = fmaf(ae, fabsf(lv.z + r1), acc[2][1]);
            acc[3][1] = fmaf(ae, fabsf(lv.w + r1), acc[3][1]);
            acc[0][2] = fmaf(ae, fabsf(lv.x + r2), acc[0][2]);
            acc[1][2] = fmaf(ae, fabsf(lv.y + r2), acc[1][2]);
            acc[2][2] = fmaf(ae, fabsf(lv.z + r2), acc[2][2]);
            acc[3][2] = fmaf(ae, fabsf(lv.w + r2), acc[3][2]);
            acc[0][3] = fmaf(ae, fabsf(lv.x + r3), acc[0][3]);
            acc[1][3] = fmaf(ae, fabsf(lv.y + r3), acc[1][3]);
            acc[2][3] = fmaf(ae, fabsf(lv.z + r3), acc[2][3]);
            acc[3][3] = fmaf(ae, fabsf(lv.w + r3), acc[3][3]);
        }
        c0 = n0_; c1 = n1_; c2 = n2_; c3 = n3_;
    }
    // fold 1.5*rsum into the partials
    #pragma unroll
    for (int i = 0; i < 4; i++)
        #pragma unroll
        for (int jj = 0; jj < 4; jj++)
            acc2P[wv][i][lane * 4 + jj] = fmaf(1.5f, rsum[jj], acc[i][jj]);
    __syncthreads();

    // ---- combine 8 octants, write block partial (coalesced)
    if (tid < 256) {
        float* Pb = P + blockIdx.x * 1024;
        #pragma unroll
        for (int i = 0; i < 4; i++) {
            float s = 0.f;
            #pragma unroll
            for (int eo = 0; eo < 8; eo++) s += acc2P[eo][i][tid];
            Pb[i * 256 + tid] = s;
        }
    }
}

// ---------------------------------------------------------------------------
// Kernel 3: epilogue — u15 + combine halves + bias + softmax + MFMA matvec.
// grid 512 = (i4-tile) x (b = blk&7); 512 thr.
// ---------------------------------------------------------------------------
__global__ __launch_bounds__(512, 2) void attn_epi_kernel(
    const float* __restrict__ x,              // (8,256,256)
    const float* __restrict__ Lp,             // (8,256,512)
    const float* __restrict__ P,              // (1024,4,256) partials
    const float* __restrict__ a,              // (512)
    const float* __restrict__ bias,           // (256,256)
    float* __restrict__ out)                  // (8,256,256)
{
    const int b    = blockIdx.x & 7;
    const int i4   = blockIdx.x >> 3;
    const int i0   = i4 * 4;
    const int tid  = threadIdx.x;
    const int wv   = tid >> 6;
    const int lane = tid & 63;

    __shared__ float u15s[4];
    __shared__ unsigned short atbf[4 * 264];

    // ---- u15[i] = 0.6 * sum_e a[e]*L[i,e]  (waves 0..3)
    if (tid < 256) {
        const int i = wv;
        const float* Lr = Lp + b * 131072 + (i0 + i) * 512 + lane * 8;
        const float* ar = a + lane * 8;
        const float4 la = *(const float4*)Lr;
        const float4 lb = *(const float4*)(Lr + 4);
        const float4 ca = *(const float4*)ar;
        const float4 cb = *(const float4*)(ar + 4);
        float p = la.x * ca.x + la.y * ca.y + la.z * ca.z + la.w * ca.w
                + lb.x * cb.x + lb.y * cb.y + lb.z * cb.z + lb.w * cb.w;
        #pragma unroll
        for (int off = 32; off; off >>= 1) p += __shfl_xor(p, off);
        if (lane == 0) u15s[i] = 0.6f * p;
    }
    __syncthreads();

    // ---- combine + softmax: wave i -> row i
    if (tid < 256) {
        const int i = wv;
        const float u15 = u15s[i];
        const float* P0 = P + ((i4 * 2 + 0) * 8 + b) * 1024 + i * 256;
        const float* P1 = P + ((i4 * 2 + 1) * 8 + b) * 1024 + i * 256;
        float v[4];
        float m = -1e30f;
        #pragma unroll
        for (int u = 0; u < 4; u++) {
            const int jj = lane + 64 * u;
            v[u] = u15 + 0.4f * (P0[jj] + P1[jj]) + bias[(i0 + i) * 256 + jj];
            m = fmaxf(m, v[u]);
        }
        #pragma unroll
        for (int off = 32; off; off >>= 1) m = fmaxf(m, __shfl_xor(m, off));
        float s = 0.f;
        #pragma unroll
        for (int u = 0; u < 4; u++) { v[u] = __expf(v[u] - m); s += v[u]; }
        #pragma unroll
        for (int off = 32; off; off >>= 1) s += __shfl_xor(s, off);
        const float inv = 1.f / s;
        #pragma unroll
        for (int u = 0; u < 4; u++)
            atbf[i * 264 + lane + 64 * u] = f2bf(v[u] * inv);
    }
    __syncthreads();

    // ---- matvec via MFMA: D[i][w] = sum_j attn[i][j] * x[b][w][j]
    {
        const int lr = lane & 15;
        const int lk = lane >> 4;
        const int arow = lr & 3;              // rows 4..15 read duplicates
        #pragma unroll
        for (int half = 0; half < 2; half++) {
            const int nt = wv + half * 8;     // 8 waves x 2 = 16 w-tiles
            f32x4 hacc = (f32x4){0.f, 0.f, 0.f, 0.f};
            const float* xw = x + b * 65536 + (nt * 16 + lr) * 256;
            #pragma unroll
            for (int kt = 0; kt < 8; kt++) {
                const bf16x8 av = *(const bf16x8*)&atbf[arow * 264 + kt * 32 + lk * 8];
                const float4 f0 = *(const float4*)(xw + kt * 32 + lk * 8);
                const float4 f1 = *(const float4*)(xw + kt * 32 + lk * 8 + 4);
                u16x8 bu;
                bu[0] = f2bf(f0.x); bu[1] = f2bf(f0.y); bu[2] = f2bf(f0.z); bu[3] = f2bf(f0.w);
                bu[4] = f2bf(f1.x); bu[5] = f2bf(f1.y); bu[6] = f2bf(f1.z); bu[7] = f2bf(f1.w);
                const bf16x8 bv = *(const bf16x8*)&bu;
                hacc = __builtin_amdgcn_mfma_f32_16x16x32_bf16(av, bv, hacc, 0, 0, 0);
            }
            if (lk == 0) {
                float4 o;
                o.x = sigmoidf_(hacc[0]);
                o.y = sigmoidf_(hacc[1]);
                o.z = sigmoidf_(hacc[2]);
                o.w = sigmoidf_(hacc[3]);
                *(float4*)(out + b * 65536 + (nt * 16 + lr) * 256 + i0) = o;
            }
        }
    }
}

extern "C" void kernel_launch(void* const* d_in, const int* in_sizes, int n_in,
                              void* d_out, int out_size, void* d_ws, size_t ws_size,
                              hipStream_t stream) {
    const float* x     = (const float*)d_in[0];
    const float* W     = (const float*)d_in[1];
    const float* b_lin = (const float*)d_in[2];
    const float* a     = (const float*)d_in[3];
    const float* bias  = (const float*)d_in[4];
    float* out = (float*)d_out;

    char* ws = (char*)d_ws;
    float*          Lp = (float*)ws;                          // 4 MB
    unsigned short* R2 = (unsigned short*)(ws + (4 << 20));   // 2 MB
    float*          P  = (float*)(ws + (6 << 20));            // 4 MB

    mfma_gemm_kernel<<<dim3(64, 8), 256, 0, stream>>>(x, W, b_lin, Lp, R2);
    attn_score_kernel<<<1024, 512, 0, stream>>>(Lp, (const unsigned int*)R2, a, P);
    attn_epi_kernel<<<512, 512, 0, stream>>>(x, Lp, P, a, bias, out);
}

// Round 13
// 107.821 us; speedup vs baseline: 1.0305x; 1.0305x over previous
//
#include <hip/hip_runtime.h>
#include <math.h>

typedef float f32x4 __attribute__((ext_vector_type(4)));
typedef float f32x2 __attribute__((ext_vector_type(2)));
typedef __bf16 bf16x8 __attribute__((ext_vector_type(8)));
typedef unsigned short u16x8 __attribute__((ext_vector_type(8)));

__device__ __forceinline__ unsigned short f2bf(float f) {
    union { float f; unsigned int u; } v; v.f = f;
    unsigned int u = v.u;
    return (unsigned short)((u + 0x7fffu + ((u >> 16) & 1u)) >> 16);  // RNE
}
__device__ __forceinline__ float bf_lo(unsigned int d) {
    union { unsigned int u; float f; } v; v.u = d << 16; return v.f;
}
__device__ __forceinline__ float bf_hi(unsigned int d) {
    union { unsigned int u; float f; } v; v.u = d & 0xffff0000u; return v.f;
}
__device__ __forceinline__ unsigned int u4get(const uint4& v, int k) {
    return k == 0 ? v.x : k == 1 ? v.y : k == 2 ? v.z : v.w;  // k compile-time
}
__device__ __forceinline__ float sigmoidf_(float v) {
    return 1.f / (1.f + __expf(-v));
}

// ---------------------------------------------------------------------------
// Kernel 1: fused convert + MFMA bf16 GEMM.  C[m][n] = sum_w A[m][w]*B[n][w].
//  left  (t<32):  A = x^T tile (transpose+cvt in LDS), B = W[e][0:256]
//                 -> Lp[b][k][e] = C + b_lin[e]   (fp32)
//  right (t>=32): A = W[e][256:512], B = x^T tile
//                 -> R2[b][(e>>3)*2048 + j*8 + (e&7)] = bf16(C)
// ---------------------------------------------------------------------------
__global__ __launch_bounds__(256) void mfma_gemm_kernel(
    const float* __restrict__ x,      // (8,256,256) x[b][w][k]
    const float* __restrict__ W,      // (512,512)
    const float* __restrict__ b_lin,  // (512)
    float* __restrict__ Lp,           // (8,256,512)
    unsigned short* __restrict__ R2)  // (8, 512e x 256j packed)
{
    const int b = blockIdx.y;
    const int t = blockIdx.x;
    const bool left = (t < 32);
    int m0, n0;
    if (left) { m0 = (t >> 3) * 64; n0 = (t & 7) * 64; }
    else      { const int tt = t - 32; m0 = (tt >> 2) * 64; n0 = (tt & 3) * 64; }

    __shared__ unsigned short As[64][72];
    __shared__ unsigned short Bs[64][72];

    unsigned short (*Ts)[72] = left ? As : Bs;   // x^T tile
    unsigned short (*Ds)[72] = left ? Bs : As;   // W tile
    const int cbase = left ? m0 : n0;            // x column base (k or j)
    const int rbase = left ? n0 : m0;            // W row base (e)
    const int coff  = left ? 0 : 256;            // W column offset

    const int tid  = threadIdx.x;
    const int wv   = tid >> 6;
    const int lane = tid & 63;
    const int wy = wv >> 1, wx = wv & 1;
    const int lr = lane & 15;
    const int lk = lane >> 4;

    const float* xb = x + b * 65536;

    f32x4 acc[2][2];
    #pragma unroll
    for (int i = 0; i < 2; i++)
        #pragma unroll
        for (int jj = 0; jj < 2; jj++) acc[i][jj] = (f32x4){0.f, 0.f, 0.f, 0.f};

    const int wl = tid >> 4;         // 0..15
    const int kg = tid & 15;         // 0..15
    const int dr = tid >> 2;         // 0..63
    const int dc = (tid & 3) * 16;

    for (int k0 = 0; k0 < 256; k0 += 64) {
        #pragma unroll
        for (int p = 0; p < 4; p++) {
            const int w = wl + 16 * p;
            const float4 v = *(const float4*)(xb + (k0 + w) * 256 + cbase + kg * 4);
            Ts[kg * 4 + 0][w] = f2bf(v.x);
            Ts[kg * 4 + 1][w] = f2bf(v.y);
            Ts[kg * 4 + 2][w] = f2bf(v.z);
            Ts[kg * 4 + 3][w] = f2bf(v.w);
        }
        {
            const float* src = W + (rbase + dr) * 512 + coff + k0 + dc;
            const float4 v0 = *(const float4*)(src);
            const float4 v1 = *(const float4*)(src + 4);
            const float4 v2 = *(const float4*)(src + 8);
            const float4 v3 = *(const float4*)(src + 12);
            u16x8 o0, o1;
            o0[0] = f2bf(v0.x); o0[1] = f2bf(v0.y); o0[2] = f2bf(v0.z); o0[3] = f2bf(v0.w);
            o0[4] = f2bf(v1.x); o0[5] = f2bf(v1.y); o0[6] = f2bf(v1.z); o0[7] = f2bf(v1.w);
            o1[0] = f2bf(v2.x); o1[1] = f2bf(v2.y); o1[2] = f2bf(v2.z); o1[3] = f2bf(v2.w);
            o1[4] = f2bf(v3.x); o1[5] = f2bf(v3.y); o1[6] = f2bf(v3.z); o1[7] = f2bf(v3.w);
            *(u16x8*)&Ds[dr][dc]     = o0;
            *(u16x8*)&Ds[dr][dc + 8] = o1;
        }
        __syncthreads();
        #pragma unroll
        for (int kk = 0; kk < 64; kk += 32) {
            const bf16x8 a0 = *(const bf16x8*)&As[wy * 32 + lr][kk + lk * 8];
            const bf16x8 a1 = *(const bf16x8*)&As[wy * 32 + 16 + lr][kk + lk * 8];
            const bf16x8 b0 = *(const bf16x8*)&Bs[wx * 32 + lr][kk + lk * 8];
            const bf16x8 b1 = *(const bf16x8*)&Bs[wx * 32 + 16 + lr][kk + lk * 8];
            acc[0][0] = __builtin_amdgcn_mfma_f32_16x16x32_bf16(a0, b0, acc[0][0], 0, 0, 0);
            acc[0][1] = __builtin_amdgcn_mfma_f32_16x16x32_bf16(a0, b1, acc[0][1], 0, 0, 0);
            acc[1][0] = __builtin_amdgcn_mfma_f32_16x16x32_bf16(a1, b0, acc[1][0], 0, 0, 0);
            acc[1][1] = __builtin_amdgcn_mfma_f32_16x16x32_bf16(a1, b1, acc[1][1], 0, 0, 0);
        }
        __syncthreads();
    }

    // C/D layout: col = lane&15, row = (lane>>4)*4 + reg
    if (left) {
        #pragma unroll
        for (int mi = 0; mi < 2; mi++) {
            #pragma unroll
            for (int ni = 0; ni < 2; ni++) {
                const int row = m0 + wy * 32 + mi * 16 + lk * 4;   // k
                const int col = n0 + wx * 32 + ni * 16 + lr;       // e
                const float bl = b_lin[col];
                #pragma unroll
                for (int r = 0; r < 4; r++)
                    Lp[b * 131072 + (row + r) * 512 + col] = acc[mi][ni][r] + bl;
            }
        }
    } else {
        unsigned short* R2b = R2 + b * 131072;
        #pragma unroll
        for (int mi = 0; mi < 2; mi++) {
            #pragma unroll
            for (int ni = 0; ni < 2; ni++) {
                const int row = m0 + wy * 32 + mi * 16 + lk * 4;   // e base (4)
                const int col = n0 + wx * 32 + ni * 16 + lr;       // j
                ushort4 o;
                o.x = f2bf(acc[mi][ni][0]);
                o.y = f2bf(acc[mi][ni][1]);
                o.z = f2bf(acc[mi][ni][2]);
                o.w = f2bf(acc[mi][ni][3]);
                *(ushort4*)(R2b + (row >> 3) * 2048 + col * 8 + (row & 7)) = o;
            }
        }
    }
}

// ---------------------------------------------------------------------------
// Kernel 2: score + softmax + MFMA matvec + sigmoid + T-store.
// grid 512 = (i-tile of 4) x (b = blk&7, XCD-local); 512 thr.
// Score: wave = e-octant (64 e), lane = j-quad (4 j). PACKED fp32 math
// (v_pk_add/max/fma) over e-pairs — R2's bf16 packing already puts e,e+1 in
// one dword. 3 pk-inst per 2 elements vs 4 scalar (~25% VALU-issue cut).
// L staged as plain rows LtI[i][e]; one b128 broadcast per (i,4e), halves
// .xy/.zw feed the two e-pairs. __launch_bounds__(512,2): 128-VGPR cap.
// score[i][j] = u15[i] + 0.4*sum_oct(acc + 1.5*rsum) + bias
// ---------------------------------------------------------------------------
__global__ __launch_bounds__(512, 2) void attn_kernel(
    const float* __restrict__ x,              // (8,256,256)
    const float* __restrict__ Lp,             // (8,256,512) fp32, b_lin folded
    const unsigned int* __restrict__ R2u,     // packed bf16 pairs
    const float* __restrict__ a,              // (512)
    const float* __restrict__ bias,           // (256,256)
    float* __restrict__ out)                  // (8,256,256)
{
    const int b    = blockIdx.x & 7;
    const int i0   = (blockIdx.x >> 3) * 4;
    const int tid  = threadIdx.x;
    const int wv   = tid >> 6;                // 0..7 = e-octant
    const int lane = tid & 63;                // j-quad index

    __shared__ float LtI[4][512];             // 8 KB   [i][e] L rows
    __shared__ float aS[512];                 // 2 KB
    __shared__ float acc2P[8][4][256];        // 32 KB  [oct][i][j] (rsum folded)
    __shared__ float u15s[4];
    __shared__ unsigned short atbf[4 * 264];  // 2.1 KB bf16 attn rows 0..3

    // ---- stage LtI (direct rows) + aS
    {
        const int i  = tid >> 7;              // 0..3
        const int e0 = (tid & 127) * 4;
        const float4 v = *(const float4*)(Lp + b * 131072 + (i0 + i) * 512 + e0);
        *(float4*)&LtI[i][e0] = v;
        aS[tid] = a[tid];
    }

    // ---- uL: waves 0..3, u15s[i] = 0.6 * sum_e a[e]*L[i,e]  (global reads)
    if (tid < 256) {
        const int i = tid >> 6, ln = tid & 63;
        const float* Lr = Lp + b * 131072 + (i0 + i) * 512 + ln * 8;
        const float* ar = a + ln * 8;
        const float4 la = *(const float4*)Lr;
        const float4 lb = *(const float4*)(Lr + 4);
        const float4 ca = *(const float4*)ar;
        const float4 cb = *(const float4*)(ar + 4);
        float p = la.x * ca.x + la.y * ca.y + la.z * ca.z + la.w * ca.w
                + lb.x * cb.x + lb.y * cb.y + lb.z * cb.z + lb.w * cb.w;
        #pragma unroll
        for (int off = 32; off; off >>= 1) p += __shfl_xor(p, off);
        if (ln == 0) u15s[i] = 0.6f * p;
    }
    __syncthreads();

    // ---- score: wave covers e in [wv*64, wv*64+64), lane covers 4 j
    const float* aq  = aS + wv * 64;
    const float* Lq0 = &LtI[0][wv * 64];
    const float* Lq1 = &LtI[1][wv * 64];
    const float* Lq2 = &LtI[2][wv * 64];
    const float* Lq3 = &LtI[3][wv * 64];
    const uint4* Rq = (const uint4*)(R2u + b * 65536) + (wv * 8) * 256 + lane * 4;

    f32x2 acc2[4][4];                         // [i][jj] packed over e-pairs
    f32x2 rsum2[4];
    #pragma unroll
    for (int i = 0; i < 4; i++)
        #pragma unroll
        for (int jj = 0; jj < 4; jj++) acc2[i][jj] = (f32x2){0.f, 0.f};
    #pragma unroll
    for (int jj = 0; jj < 4; jj++) rsum2[jj] = (f32x2){0.f, 0.f};

    uint4 c0 = Rq[0], c1 = Rq[1], c2 = Rq[2], c3 = Rq[3];
    #pragma unroll 1
    for (int tk = 0; tk < 8; tk++) {
        uint4 n0_, n1_, n2_, n3_;
        if (tk < 7) {
            const uint4* Rn = Rq + (tk + 1) * 256;
            n0_ = Rn[0]; n1_ = Rn[1]; n2_ = Rn[2]; n3_ = Rn[3];
        }
        #pragma unroll
        for (int g = 0; g < 2; g++) {         // 4-e group -> b128 broadcasts
            const int eb = tk * 8 + g * 4;
            const float4 a4  = *(const float4*)&aq[eb];
            const float4 l04 = *(const float4*)&Lq0[eb];
            const float4 l14 = *(const float4*)&Lq1[eb];
            const float4 l24 = *(const float4*)&Lq2[eb];
            const float4 l34 = *(const float4*)&Lq3[eb];
            #pragma unroll
            for (int d2 = 0; d2 < 2; d2++) {  // e-pair within group
                const int dwi = g * 2 + d2;   // dword index 0..3
                f32x2 a2, l0, l1, l2, l3;
                if (d2 == 0) {
                    a2 = (f32x2){a4.x, a4.y};
                    l0 = (f32x2){l04.x, l04.y};
                    l1 = (f32x2){l14.x, l14.y};
                    l2 = (f32x2){l24.x, l24.y};
                    l3 = (f32x2){l34.x, l34.y};
                } else {
                    a2 = (f32x2){a4.z, a4.w};
                    l0 = (f32x2){l04.z, l04.w};
                    l1 = (f32x2){l14.z, l14.w};
                    l2 = (f32x2){l24.z, l24.w};
                    l3 = (f32x2){l34.z, l34.w};
                }
                #pragma unroll
                for (int jj = 0; jj < 4; jj++) {
                    const unsigned int dw = u4get(jj == 0 ? c0 : jj == 1 ? c1
                                                : jj == 2 ? c2 : c3, dwi);
                    f32x2 r2;
                    r2.x = bf_lo(dw);
                    r2.y = bf_hi(dw);
                    rsum2[jj] = a2 * r2 + rsum2[jj];           // v_pk_fma
                    f32x2 p;
                    p = l0 + r2;
                    acc2[0][jj] = a2 * __builtin_elementwise_max(p, -p) + acc2[0][jj];
                    p = l1 + r2;
                    acc2[1][jj] = a2 * __builtin_elementwise_max(p, -p) + acc2[1][jj];
                    p = l2 + r2;
                    acc2[2][jj] = a2 * __builtin_elementwise_max(p, -p) + acc2[2][jj];
                    p = l3 + r2;
                    acc2[3][jj] = a2 * __builtin_elementwise_max(p, -p) + acc2[3][jj];
                }
            }
        }
        c0 = n0_; c1 = n1_; c2 = n2_; c3 = n3_;
    }
    // horizontal combine + fold 1.5*rsum into the partials
    #pragma unroll
    for (int jj = 0; jj < 4; jj++) {
        const float rs = rsum2[jj].x + rsum2[jj].y;
        #pragma unroll
        for (int i = 0; i < 4; i++)
            acc2P[wv][i][lane * 4 + jj] =
                fmaf(1.5f, rs, acc2[i][jj].x + acc2[i][jj].y);
    }
    __syncthreads();

    // ---- softmax (8-way combine folded in): wave i (tid<256) -> row i
    if (tid < 256) {
        const int i = tid >> 6, ln = tid & 63;
        const float u15 = u15s[i];
        float v[4];
        float m = -1e30f;
        #pragma unroll
        for (int u = 0; u < 4; u++) {
            const int jj = ln + 64 * u;
            float ab = 0.f;
            #pragma unroll
            for (int eo = 0; eo < 8; eo++) ab += acc2P[eo][i][jj];
            v[u] = u15 + 0.4f * ab + bias[(i0 + i) * 256 + jj];
            m = fmaxf(m, v[u]);
        }
        #pragma unroll
        for (int off = 32; off; off >>= 1) m = fmaxf(m, __shfl_xor(m, off));
        float s = 0.f;
        #pragma unroll
        for (int u = 0; u < 4; u++) { v[u] = __expf(v[u] - m); s += v[u]; }
        #pragma unroll
        for (int off = 32; off; off >>= 1) s += __shfl_xor(s, off);
        const float inv = 1.f / s;
        #pragma unroll
        for (int u = 0; u < 4; u++)
            atbf[i * 264 + ln + 64 * u] = f2bf(v[u] * inv);
    }
    __syncthreads();

    // ---- matvec via MFMA: D[i][w] = sum_j attn[i][j] * x[b][w][j]
    {
        const int lr = lane & 15;
        const int lk = lane >> 4;
        const int arow = lr & 3;              // rows 4..15 read duplicates
        #pragma unroll
        for (int half = 0; half < 2; half++) {
            const int nt = wv + half * 8;
            f32x4 hacc = (f32x4){0.f, 0.f, 0.f, 0.f};
            const float* xw = x + b * 65536 + (nt * 16 + lr) * 256;
            #pragma unroll
            for (int kt = 0; kt < 8; kt++) {
                const bf16x8 av = *(const bf16x8*)&atbf[arow * 264 + kt * 32 + lk * 8];
                const float4 f0 = *(const float4*)(xw + kt * 32 + lk * 8);
                const float4 f1 = *(const float4*)(xw + kt * 32 + lk * 8 + 4);
                u16x8 bu;
                bu[0] = f2bf(f0.x); bu[1] = f2bf(f0.y); bu[2] = f2bf(f0.z); bu[3] = f2bf(f0.w);
                bu[4] = f2bf(f1.x); bu[5] = f2bf(f1.y); bu[6] = f2bf(f1.z); bu[7] = f2bf(f1.w);
                const bf16x8 bv = *(const bf16x8*)&bu;
                hacc = __builtin_amdgcn_mfma_f32_16x16x32_bf16(av, bv, hacc, 0, 0, 0);
            }
            if (lk == 0) {
                float4 o;
                o.x = sigmoidf_(hacc[0]);
                o.y = sigmoidf_(hacc[1]);
                o.z = sigmoidf_(hacc[2]);
                o.w = sigmoidf_(hacc[3]);
                *(float4*)(out + b * 65536 + (nt * 16 + lr) * 256 + i0) = o;
            }
        }
    }
}

extern "C" void kernel_launch(void* const* d_in, const int* in_sizes, int n_in,
                              void* d_out, int out_size, void* d_ws, size_t ws_size,
                              hipStream_t stream) {
    const float* x     = (const float*)d_in[0];
    const float* W     = (const float*)d_in[1];
    const float* b_lin = (const float*)d_in[2];
    const float* a     = (const float*)d_in[3];
    const float* bias  = (const float*)d_in[4];
    float* out = (float*)d_out;

    char* ws = (char*)d_ws;
    float*          Lp = (float*)ws;                          // 4 MB
    unsigned short* R2 = (unsigned short*)(ws + (4 << 20));   // 2 MB
    float*          P  = (float*)(ws + (6 << 20));            // unused

    (void)P;
    mfma_gemm_kernel<<<dim3(64, 8), 256, 0, stream>>>(x, W, b_lin, Lp, R2);
    attn_kernel<<<512, 512, 0, stream>>>(x, Lp, (const unsigned int*)R2, a, bias, out);
}